// Round 2
// baseline (31.394 us; speedup 1.0000x reference)
//
#include <hip/hip_runtime.h>
#include <stdint.h>

// ---------------------------------------------------------------------------
// BondMatrixMessage: messages[b,e,i] = sum_{k,j} bond[b,e,k] W[k,i,j] src[b,e,j]
// Recast as GEMM C[16384 x 64] = A[16384 x 4096] @ W2[4096 x 64],
//   A[e, k*64+j] = bond[e,k]*src[e,j]   (generated in registers, never stored)
//   W2 chunk for k == bond_transform row k (layout [i][j]) cast to f16 (prep)
// 256 blocks x 256 thr; 4 waves = 2 col-halves x 2 k-halves of 32x32x16 f16
// MFMA; k-halves pair-reduced via LDS. W2 staged with global_load_lds +
// XOR-preswizzled GLOBAL source -> linear LDS dest, matching XOR on ds_read
// (rule #21: both-sides-or-neither).
// conn is int32 (harness converts int64 -> int32): src idx = conn[e*2].
// ---------------------------------------------------------------------------

#define NATOMS 256
#define DIM 64
#define BM 64

typedef _Float16 f16;
typedef _Float16 f16x2 __attribute__((ext_vector_type(2)));
typedef _Float16 f16x4 __attribute__((ext_vector_type(4)));
typedef _Float16 f16x8 __attribute__((ext_vector_type(8)));
typedef float f32x16 __attribute__((ext_vector_type(16)));

#define AS1 __attribute__((address_space(1)))
#define AS3 __attribute__((address_space(3)))

union H8 { f16x8 v8; f16x2 v2[4]; };

static __device__ __forceinline__ void gll16(const void* g, void* l) {
    __builtin_amdgcn_global_load_lds((AS1 void*)(uintptr_t)g, (AS3 void*)l, 16, 0, 0);
}

// prep: element-wise f32 -> f16 cast of bond_transform (64 x 4096), layout kept
__global__ __launch_bounds__(256) void prep_w2h(const float* __restrict__ bt,
                                                f16* __restrict__ w2h) {
    int t = blockIdx.x * 256 + threadIdx.x;          // 65536 threads x float4
    float4 v = reinterpret_cast<const float4*>(bt)[t];
    f16x4 h = { (f16)v.x, (f16)v.y, (f16)v.z, (f16)v.w };
    reinterpret_cast<f16x4*>(w2h)[t] = h;
}

__global__ __launch_bounds__(256, 1) void bond_msg(
    const float* __restrict__ atom, const float* __restrict__ bond,
    const int* __restrict__ conn, const f16* __restrict__ w2h,
    float* __restrict__ out)
{
    // LDS map: [0,32KB) Bs[p(2)][kh(2)][8KB = 64 i x 128B]
    //          [32KB,48KB) bondT dup-f16 u32[64][64] (m XOR-swizzled)
    //          [48KB,64KB) raw bond tile f32[m][k]; reused as kh-reduce buffer
    __shared__ __align__(16) unsigned char smem[65536];

    const int tid  = threadIdx.x;
    const int lane = tid & 63;
    const int w    = tid >> 6;     // wave 0..3
    const int wc   = w & 1;        // column half (i: 0-31 / 32-63)
    const int kh   = w >> 1;       // k half (k: 0-31 / 32-63)
    const int lo   = lane & 31;
    const int hi   = lane >> 5;
    const int blk  = blockIdx.x;
    const int bond0 = blk * BM;    // 8 blocks per batch; never straddles a batch

    // ---- src atom gather -> registers (f16 pairs). Rows m0=lo, m1=lo+32.
    const int m0 = lo, m1 = lo + 32;
    const int ia0 = conn[(bond0 + m0) * 2];   // int32 conn, element [e][0]
    const int ia1 = conn[(bond0 + m1) * 2];
    const float* ar0 = atom + (size_t)(blk >> 3) * (NATOMS * DIM) + (size_t)ia0 * DIM;
    const float* ar1 = atom + (size_t)(blk >> 3) * (NATOMS * DIM) + (size_t)ia1 * DIM;
    f16x2 srcv[2][4][4];   // [m-frag][K-step s][pair] ; j = s*16 + hi*8 + {0..7}
    #pragma unroll
    for (int s = 0; s < 4; ++s) {
        const int j0 = s * 16 + hi * 8;
        float4 p0 = *reinterpret_cast<const float4*>(ar0 + j0);
        float4 p1 = *reinterpret_cast<const float4*>(ar0 + j0 + 4);
        float4 q0 = *reinterpret_cast<const float4*>(ar1 + j0);
        float4 q1 = *reinterpret_cast<const float4*>(ar1 + j0 + 4);
        srcv[0][s][0] = (f16x2){ (f16)p0.x, (f16)p0.y };
        srcv[0][s][1] = (f16x2){ (f16)p0.z, (f16)p0.w };
        srcv[0][s][2] = (f16x2){ (f16)p1.x, (f16)p1.y };
        srcv[0][s][3] = (f16x2){ (f16)p1.z, (f16)p1.w };
        srcv[1][s][0] = (f16x2){ (f16)q0.x, (f16)q0.y };
        srcv[1][s][1] = (f16x2){ (f16)q0.z, (f16)q0.w };
        srcv[1][s][2] = (f16x2){ (f16)q1.x, (f16)q1.y };
        srcv[1][s][3] = (f16x2){ (f16)q1.z, (f16)q1.w };
    }

    // W2 chunk staging: wave (kh,wc) stages its 4KB quarter.
    // LDS slot (iloc,u) <- global 16B chunk (iloc, u ^ (iloc&7)).
    auto stage_w2 = [&](int p, int it) {
        const int kg = kh * 32 + it;
        const char* gsrc = reinterpret_cast<const char*>(w2h) + (size_t)kg * 8192;
        const unsigned lbase = (unsigned)(p * 16384 + kh * 8192 + wc * 4096);
        #pragma unroll
        for (int c = 0; c < 4; ++c) {
            const int iloc = wc * 32 + c * 8 + (lane >> 3);
            const int u = lane & 7;
            const int goff = iloc * 128 + ((u ^ (iloc & 7)) << 4);
            gll16(gsrc + goff, smem + lbase + c * 1024);
        }
    };

    // ---- prologue: stage raw bond tile (16KB contiguous) + first W2 chunks
    {
        const char* gb = reinterpret_cast<const char*>(bond + (size_t)bond0 * DIM);
        #pragma unroll
        for (int c = 0; c < 4; ++c)
            gll16(gb + w * 4096 + c * 1024 + lane * 16, smem + 49152 + w * 4096 + c * 1024);
    }
    stage_w2(0, 0);
    __syncthreads();

    // ---- bond transpose to dup'd-f16 bondT[k][m ^ (k&31)] (conflict-light)
    {
        const float* bl = reinterpret_cast<const float*>(smem + 49152);
        unsigned* btw = reinterpret_cast<unsigned*>(smem + 32768);
        const int k = lane;
        #pragma unroll
        for (int mm = 0; mm < 16; ++mm) {
            const int m = w * 16 + mm;
            const f16 hh = (f16)bl[m * 64 + k];
            const f16x2 d = { hh, hh };
            btw[k * 64 + (m ^ (k & 31))] = __builtin_bit_cast(unsigned, d);
        }
    }
    __syncthreads();

    // ---- main loop: each wave does 32 k-values; 8 MFMA / iter
    f32x16 acc0 = {};
    f32x16 acc1 = {};
    const unsigned* btl = reinterpret_cast<const unsigned*>(smem + 32768);
    const int i = lo + 32 * wc;   // output column / B-operand lane col

    for (int it = 0; it < 32; ++it) {
        const int p = it & 1;
        if (it + 1 < 32) stage_w2(1 - p, it + 1);   // prefetch next chunk

        const int kg = kh * 32 + it;
        const f16x2 b0 = __builtin_bit_cast(f16x2, btl[kg * 64 + (m0 ^ (kg & 31))]);
        const f16x2 b1 = __builtin_bit_cast(f16x2, btl[kg * 64 + (m1 ^ (kg & 31))]);
        const unsigned bsbase = (unsigned)(p * 16384 + kh * 8192);

        #pragma unroll
        for (int s = 0; s < 4; ++s) {
            const int u = (2 * s + hi) ^ (i & 7);
            f16x8 bf = *reinterpret_cast<const f16x8*>(smem + bsbase + i * 128 + u * 16);
            H8 a0, a1;
            #pragma unroll
            for (int t = 0; t < 4; ++t) {
                a0.v2[t] = b0 * srcv[0][s][t];   // v_pk_mul_f16: A = bond*src
                a1.v2[t] = b1 * srcv[1][s][t];
            }
            acc0 = __builtin_amdgcn_mfma_f32_32x32x16_f16(a0.v8, bf, acc0, 0, 0, 0);
            acc1 = __builtin_amdgcn_mfma_f32_32x32x16_f16(a1.v8, bf, acc1, 0, 0, 0);
        }
        __syncthreads();   // drains gll vmcnt; buffer flip safe
    }

    // ---- epilogue: reduce k-halves (kh=1 -> LDS -> kh=0 adds), write C
    if (kh == 1) {
        #pragma unroll
        for (int g = 0; g < 4; ++g) {
            float4 v0 = { acc0[4*g+0], acc0[4*g+1], acc0[4*g+2], acc0[4*g+3] };
            *reinterpret_cast<float4*>(smem + 49152 + wc*8192 + g*1024 + lane*16) = v0;
            float4 v1 = { acc1[4*g+0], acc1[4*g+1], acc1[4*g+2], acc1[4*g+3] };
            *reinterpret_cast<float4*>(smem + 49152 + wc*8192 + (g+4)*1024 + lane*16) = v1;
        }
    }
    __syncthreads();
    if (kh == 0) {
        #pragma unroll
        for (int g = 0; g < 4; ++g) {
            float4 v0 = *reinterpret_cast<const float4*>(smem + 49152 + wc*8192 + g*1024 + lane*16);
            acc0[4*g+0] += v0.x; acc0[4*g+1] += v0.y; acc0[4*g+2] += v0.z; acc0[4*g+3] += v0.w;
            float4 v1 = *reinterpret_cast<const float4*>(smem + 49152 + wc*8192 + (g+4)*1024 + lane*16);
            acc1[4*g+0] += v1.x; acc1[4*g+1] += v1.y; acc1[4*g+2] += v1.z; acc1[4*g+3] += v1.w;
        }
        const int colb = 32 * wc + lo;
        #pragma unroll
        for (int r = 0; r < 16; ++r) {
            // verified C/D map: col = lane&31, row = (r&3) + 8*(r>>2) + 4*(lane>>5)
            const int rl = (r & 3) + 8 * (r >> 2) + 4 * hi;
            out[(size_t)(bond0 + rl) * 64 + colb]      = acc0[r];
            out[(size_t)(bond0 + 32 + rl) * 64 + colb] = acc1[r];
        }
    }
}

// ---- fallback (no workspace needed): f32, LDS-staged W row per k. Slow but
// correct; only used if ws_size < 512KB.
__global__ __launch_bounds__(256) void bond_fallback(
    const float* __restrict__ atom, const float* __restrict__ bond,
    const int* __restrict__ conn, const float* __restrict__ bt,
    float* __restrict__ out)
{
    __shared__ float Wk[4096];     // W[k][i][j] for current k
    __shared__ float srcs[4][64];
    __shared__ float bnds[4][64];
    const int blk = blockIdx.x;    // 4096 blocks x 4 bonds
    const int e0 = blk * 4;
    const int b = e0 >> 9;         // 512 bonds per batch
    const int t = threadIdx.x;
    const int il = t & 63, eg = t >> 6;
    const int e = e0 + eg;
    const int ia = conn[e * 2];
    srcs[eg][il] = atom[(size_t)b * (NATOMS * DIM) + (size_t)ia * DIM + il];
    bnds[eg][il] = bond[(size_t)e * DIM + il];
    float acc = 0.f;
    for (int k = 0; k < 64; ++k) {
        __syncthreads();
        #pragma unroll
        for (int c = 0; c < 4; ++c) {
            float4 v = reinterpret_cast<const float4*>(bt + (size_t)k * 4096)[t + c * 256];
            reinterpret_cast<float4*>(Wk)[t + c * 256] = v;
        }
        __syncthreads();
        float s = 0.f;
        #pragma unroll
        for (int j = 0; j < 64; ++j) s += Wk[il * 64 + j] * srcs[eg][j];
        acc += bnds[eg][k] * s;
    }
    out[(size_t)e * DIM + il] = acc;
}

extern "C" void kernel_launch(void* const* d_in, const int* in_sizes, int n_in,
                              void* d_out, int out_size, void* d_ws, size_t ws_size,
                              hipStream_t stream) {
    const float* atom = (const float*)d_in[0];   // (32,256,64) f32
    const float* bond = (const float*)d_in[1];   // (32,512,64) f32
    const int*   conn = (const int*)d_in[2];     // (32,512,2) int32 (converted)
    const float* bt   = (const float*)d_in[3];   // (64,4096) f32
    float* out = (float*)d_out;                  // (32,512,64) f32

    if (ws_size >= (size_t)64 * 4096 * sizeof(f16)) {
        f16* w2h = (f16*)d_ws;                   // 512 KB scratch
        prep_w2h<<<256, 256, 0, stream>>>(bt, w2h);
        bond_msg<<<256, 256, 0, stream>>>(atom, bond, conn, w2h, out);
    } else {
        bond_fallback<<<4096, 256, 0, stream>>>(atom, bond, conn, bt, out);
    }
}

// Round 3
// 24.045 us; speedup vs baseline: 1.3056x; 1.3056x over previous
//
#include <hip/hip_runtime.h>
#include <stdint.h>

// ---------------------------------------------------------------------------
// BondMatrixMessage: messages[b,e,i] = sum_{k,j} bond[b,e,k] W[k,i,j] src[b,e,j]
// GEMM recast: C[16384 x 64] = A[16384 x 4096] @ W2[4096 x 64]
//   A[e, k*64+j] = bond[e,k]*src[e,j]  (built in registers via v_pk_mul_f16)
//   W2[k*64+j][i] = bt[k][i*64+j], prep-cast to f16 in MFMA-FRAGMENT ORDER so
//   the main loop B-loads are coalesced global_load_dwordx4 -> registers.
// 256 blocks x 256 thr (1 blk/CU); 4 waves = 2 col-halves (wc) x 2 k-halves
// (kh) of v_mfma_f32_32x32x16_f16; kh pair-reduced via LDS at the end.
// MAIN LOOP HAS NO BARRIERS and no LDS B-traffic: B is software-pipelined
// 1 iter ahead in two named register sets (static indexing, rule #20).
// conn is int32 (harness narrows int64): src idx = conn[e*2].
// ---------------------------------------------------------------------------

#define NATOMS 256
#define DIM 64
#define BM 64

typedef _Float16 f16;
typedef _Float16 f16x2 __attribute__((ext_vector_type(2)));
typedef _Float16 f16x8 __attribute__((ext_vector_type(8)));
typedef float f32x16 __attribute__((ext_vector_type(16)));

#define AS1 __attribute__((address_space(1)))
#define AS3 __attribute__((address_space(3)))

union H8 { f16x8 v8; f16x2 v2[4]; };

static __device__ __forceinline__ void gll16(const void* g, void* l) {
    __builtin_amdgcn_global_load_lds((AS1 void*)(uintptr_t)g, (AS3 void*)l, 16, 0, 0);
}

// prep: cast + permute bt (64 x 4096 f32) into fragment-ordered f16 chunks.
// Row kg holds 512 x 16B chunks; chunk c: wc=c>>8, s=(c>>6)&3, l=c&63,
// content = bt[kg][i*64 + u*8 .. +8] with i=(l&31)+32*wc, u=2*s+(l>>5).
// Main-loop lane l of wave (kh,wc) then reads chunk (kg, wc, s, l) -- fully
// coalesced 1KB per wave-instruction.
__global__ __launch_bounds__(256) void prep_w2f(const float* __restrict__ bt,
                                                f16* __restrict__ w2f) {
    const int d  = blockIdx.x * 256 + threadIdx.x;   // 32768 chunks total
    const int kg = d >> 9, c = d & 511;
    const int wcq = c >> 8, s = (c >> 6) & 3, l = c & 63;
    const int i = (l & 31) + 32 * wcq;
    const int u = 2 * s + (l >> 5);
    const float* src = bt + (size_t)kg * 4096 + i * 64 + u * 8;
    const float4 p = *reinterpret_cast<const float4*>(src);
    const float4 q = *reinterpret_cast<const float4*>(src + 4);
    const f16x8 h = { (f16)p.x, (f16)p.y, (f16)p.z, (f16)p.w,
                      (f16)q.x, (f16)q.y, (f16)q.z, (f16)q.w };
    reinterpret_cast<f16x8*>(w2f)[d] = h;
}

__global__ __launch_bounds__(256, 1) void bond_msg(
    const float* __restrict__ atom, const float* __restrict__ bond,
    const int* __restrict__ conn, const f16* __restrict__ w2f,
    float* __restrict__ out)
{
    // LDS: [0,16KB) raw bond tile f32[m][k], reused as kh-reduce buffer
    //      [16KB,32KB) bondT dup'd-f16 u32[64][64] (m XOR-swizzled, 2-way-free)
    __shared__ __align__(16) unsigned char smem[32768];

    const int tid  = threadIdx.x;
    const int lane = tid & 63;
    const int w    = tid >> 6;     // wave 0..3
    const int wc   = w & 1;        // column half (i: 0-31 / 32-63)
    const int kh   = w >> 1;       // k half (k: 0-31 / 32-63)
    const int lo   = lane & 31;
    const int hi   = lane >> 5;
    const int blk  = blockIdx.x;
    const int bond0 = blk * BM;    // 8 blocks per batch; never straddles

    // ---- src atom gather -> registers (f16 pairs). Rows m0=lo, m1=lo+32.
    const int m0 = lo, m1 = lo + 32;
    const int ia0 = conn[(bond0 + m0) * 2];
    const int ia1 = conn[(bond0 + m1) * 2];
    const float* ar0 = atom + (size_t)(blk >> 3) * (NATOMS * DIM) + (size_t)ia0 * DIM;
    const float* ar1 = atom + (size_t)(blk >> 3) * (NATOMS * DIM) + (size_t)ia1 * DIM;
    f16x2 srcv[2][4][4];   // [m-frag][K-step s][pair]; j = s*16 + hi*8 + {0..7}
    #pragma unroll
    for (int s = 0; s < 4; ++s) {
        const int j0 = s * 16 + hi * 8;
        float4 p0 = *reinterpret_cast<const float4*>(ar0 + j0);
        float4 p1 = *reinterpret_cast<const float4*>(ar0 + j0 + 4);
        float4 q0 = *reinterpret_cast<const float4*>(ar1 + j0);
        float4 q1 = *reinterpret_cast<const float4*>(ar1 + j0 + 4);
        srcv[0][s][0] = (f16x2){ (f16)p0.x, (f16)p0.y };
        srcv[0][s][1] = (f16x2){ (f16)p0.z, (f16)p0.w };
        srcv[0][s][2] = (f16x2){ (f16)p1.x, (f16)p1.y };
        srcv[0][s][3] = (f16x2){ (f16)p1.z, (f16)p1.w };
        srcv[1][s][0] = (f16x2){ (f16)q0.x, (f16)q0.y };
        srcv[1][s][1] = (f16x2){ (f16)q0.z, (f16)q0.w };
        srcv[1][s][2] = (f16x2){ (f16)q1.x, (f16)q1.y };
        srcv[1][s][3] = (f16x2){ (f16)q1.z, (f16)q1.w };
    }

    // ---- prologue: stage raw bond tile (16KB contiguous) to LDS
    {
        const char* gb = reinterpret_cast<const char*>(bond + (size_t)bond0 * DIM);
        #pragma unroll
        for (int c = 0; c < 4; ++c)
            gll16(gb + w * 4096 + c * 1024 + lane * 16, smem + w * 4096 + c * 1024);
    }
    __syncthreads();   // drains gll vmcnt

    // ---- transpose bond to dup'd-f16 bondT[k][m ^ (k&31)]
    {
        const float* bl = reinterpret_cast<const float*>(smem);
        unsigned* btw = reinterpret_cast<unsigned*>(smem + 16384);
        const int k = lane;
        #pragma unroll
        for (int mm = 0; mm < 16; ++mm) {
            const int m = w * 16 + mm;
            const f16 hh = (f16)bl[m * 64 + k];
            const f16x2 d = { hh, hh };
            btw[k * 64 + (m ^ (k & 31))] = __builtin_bit_cast(unsigned, d);
        }
    }
    __syncthreads();

    // ---- main loop: barrier-free, B pipelined in registers 1 iter ahead
    f32x16 acc0 = {};
    f32x16 acc1 = {};
    const unsigned* btl = reinterpret_cast<const unsigned*>(smem + 16384);
    // this wave's B-fragment base: chunk (kg, wc, s, lane)
    const char* gw = reinterpret_cast<const char*>(w2f)
                   + (size_t)kh * 32 * 8192 + wc * 4096 + lane * 16;

    f16x8 bufA[4], bufB[4];
    #define LOADIT(buf, it) do {                                          \
        const char* _p = gw + (it) * 8192;                                \
        buf[0] = *reinterpret_cast<const f16x8*>(_p);                     \
        buf[1] = *reinterpret_cast<const f16x8*>(_p + 1024);              \
        buf[2] = *reinterpret_cast<const f16x8*>(_p + 2048);              \
        buf[3] = *reinterpret_cast<const f16x8*>(_p + 3072);              \
    } while (0)

    #define COMPIT(buf, it) do {                                          \
        const int _kg = kh * 32 + (it);                                   \
        const f16x2 _b0 = __builtin_bit_cast(f16x2,                       \
            btl[_kg * 64 + (m0 ^ (_kg & 31))]);                           \
        const f16x2 _b1 = __builtin_bit_cast(f16x2,                       \
            btl[_kg * 64 + (m1 ^ (_kg & 31))]);                           \
        _Pragma("unroll")                                                 \
        for (int s = 0; s < 4; ++s) {                                     \
            H8 _a0, _a1;                                                  \
            _Pragma("unroll")                                             \
            for (int t = 0; t < 4; ++t) {                                 \
                _a0.v2[t] = _b0 * srcv[0][s][t];                          \
                _a1.v2[t] = _b1 * srcv[1][s][t];                          \
            }                                                             \
            acc0 = __builtin_amdgcn_mfma_f32_32x32x16_f16(_a0.v8, buf[s], acc0, 0, 0, 0); \
            acc1 = __builtin_amdgcn_mfma_f32_32x32x16_f16(_a1.v8, buf[s], acc1, 0, 0, 0); \
        }                                                                 \
    } while (0)

    LOADIT(bufA, 0);
    for (int it = 0; it < 32; it += 2) {
        LOADIT(bufB, it + 1);
        COMPIT(bufA, it);
        if (it + 2 < 32) LOADIT(bufA, it + 2);
        COMPIT(bufB, it + 1);
    }

    // ---- epilogue: reduce k-halves through LDS (region [0,16KB)), write C
    if (kh == 1) {
        #pragma unroll
        for (int g = 0; g < 4; ++g) {
            float4 v0 = { acc0[4*g+0], acc0[4*g+1], acc0[4*g+2], acc0[4*g+3] };
            *reinterpret_cast<float4*>(smem + wc*8192 + g*1024 + lane*16) = v0;
            float4 v1 = { acc1[4*g+0], acc1[4*g+1], acc1[4*g+2], acc1[4*g+3] };
            *reinterpret_cast<float4*>(smem + wc*8192 + (g+4)*1024 + lane*16) = v1;
        }
    }
    __syncthreads();
    if (kh == 0) {
        #pragma unroll
        for (int g = 0; g < 4; ++g) {
            float4 v0 = *reinterpret_cast<const float4*>(smem + wc*8192 + g*1024 + lane*16);
            acc0[4*g+0] += v0.x; acc0[4*g+1] += v0.y; acc0[4*g+2] += v0.z; acc0[4*g+3] += v0.w;
            float4 v1 = *reinterpret_cast<const float4*>(smem + wc*8192 + (g+4)*1024 + lane*16);
            acc1[4*g+0] += v1.x; acc1[4*g+1] += v1.y; acc1[4*g+2] += v1.z; acc1[4*g+3] += v1.w;
        }
        const int colb = 32 * wc + lo;
        #pragma unroll
        for (int r = 0; r < 16; ++r) {
            // C/D map: col = lane&31, row = (r&3) + 8*(r>>2) + 4*(lane>>5)
            const int rl = (r & 3) + 8 * (r >> 2) + 4 * hi;
            out[(size_t)(bond0 + rl) * 64 + colb]      = acc0[r];
            out[(size_t)(bond0 + 32 + rl) * 64 + colb] = acc1[r];
        }
    }
}

// ---- fallback (used only if ws_size < 512KB): f32, LDS-staged, correct.
__global__ __launch_bounds__(256) void bond_fallback(
    const float* __restrict__ atom, const float* __restrict__ bond,
    const int* __restrict__ conn, const float* __restrict__ bt,
    float* __restrict__ out)
{
    __shared__ float Wk[4096];
    __shared__ float srcs[4][64];
    __shared__ float bnds[4][64];
    const int blk = blockIdx.x;
    const int e0 = blk * 4;
    const int b = e0 >> 9;
    const int t = threadIdx.x;
    const int il = t & 63, eg = t >> 6;
    const int e = e0 + eg;
    const int ia = conn[e * 2];
    srcs[eg][il] = atom[(size_t)b * (NATOMS * DIM) + (size_t)ia * DIM + il];
    bnds[eg][il] = bond[(size_t)e * DIM + il];
    float acc = 0.f;
    for (int k = 0; k < 64; ++k) {
        __syncthreads();
        #pragma unroll
        for (int c = 0; c < 4; ++c) {
            float4 v = reinterpret_cast<const float4*>(bt + (size_t)k * 4096)[t + c * 256];
            reinterpret_cast<float4*>(Wk)[t + c * 256] = v;
        }
        __syncthreads();
        float s = 0.f;
        #pragma unroll
        for (int j = 0; j < 64; ++j) s += Wk[il * 64 + j] * srcs[eg][j];
        acc += bnds[eg][k] * s;
    }
    out[(size_t)e * DIM + il] = acc;
}

extern "C" void kernel_launch(void* const* d_in, const int* in_sizes, int n_in,
                              void* d_out, int out_size, void* d_ws, size_t ws_size,
                              hipStream_t stream) {
    const float* atom = (const float*)d_in[0];   // (32,256,64) f32
    const float* bond = (const float*)d_in[1];   // (32,512,64) f32
    const int*   conn = (const int*)d_in[2];     // (32,512,2) int32 (narrowed)
    const float* bt   = (const float*)d_in[3];   // (64,4096) f32
    float* out = (float*)d_out;                  // (32,512,64) f32

    if (ws_size >= (size_t)64 * 4096 * sizeof(f16)) {
        f16* w2f = (f16*)d_ws;                   // 512 KB scratch
        prep_w2f<<<128, 256, 0, stream>>>(bt, w2f);
        bond_msg<<<256, 256, 0, stream>>>(atom, bond, conn, w2f, out);
    } else {
        bond_fallback<<<4096, 256, 0, stream>>>(atom, bond, conn, bt, out);
    }
}